// Round 15
// baseline (171.721 us; speedup 1.0000x reference)
//
#include <hip/hip_runtime.h>
#include <hip/hip_bf16.h>

#define B_ 16
#define N_ 256
#define D_ 512
#define H_ 8
#define DK_ 64

typedef unsigned short u16;
typedef __attribute__((ext_vector_type(8))) short bf16x8;
typedef __attribute__((ext_vector_type(4))) float f32x4;

__device__ __forceinline__ float bf2f(u16 u) {
    union { unsigned int i; float f; } v;
    v.i = ((unsigned int)u) << 16;
    return v.f;
}
__device__ __forceinline__ u16 f2bf(float f) {
    union { float f; unsigned int i; } v;
    v.f = f;
    unsigned int x = v.i;
    unsigned int r = (x >> 16) & 1u;
    x += 0x7fffu + r;           // round-to-nearest-even
    return (u16)(x >> 16);
}

// ---------------------------------------------------------------------------
// k_prep_lite: blocks 0..1023 wtrans | 1024..4095 X->bf16 cvt.
// (Only what gemm_qkv depends on; geo moved to overlap with the GEMM.)
// ---------------------------------------------------------------------------
__global__ __launch_bounds__(256) void k_prep_lite(const float* __restrict__ W0,
                                                   const float* __restrict__ W1,
                                                   const float* __restrict__ W2,
                                                   const float* __restrict__ W3,
                                                   u16* __restrict__ Wt,
                                                   const float* __restrict__ X0,
                                                   const float* __restrict__ X1,
                                                   const float* __restrict__ X2,
                                                   u16* __restrict__ Xb) {
    const int tid = threadIdx.x;
    const int bid = blockIdx.x;
    if (bid < 1024) {
        __shared__ float tt[32][33];
        int t = bid;
        int z = t >> 8, yb = (t >> 4) & 15, xb = t & 15;
        const float* W = (z == 0) ? W0 : (z == 1) ? W1 : (z == 2) ? W2 : W3;
        u16* dst = Wt + (size_t)z * 262144;
        const int kb = yb * 32, nb = xb * 32;
#pragma unroll
        for (int r = 0; r < 4; ++r) {
            int p = r * 256 + tid;
            tt[p >> 5][p & 31] = W[(size_t)(kb + (p >> 5)) * 512 + nb + (p & 31)];
        }
        __syncthreads();
#pragma unroll
        for (int r = 0; r < 4; ++r) {
            int p = r * 256 + tid;
            dst[(size_t)(nb + (p >> 5)) * 512 + kb + (p & 31)] = f2bf(tt[p & 31][p >> 5]);
        }
    } else {
        int t = bid - 1024;
        int z = t >> 10, x = t & 1023;
        const float* X = (z == 0) ? X0 : (z == 1) ? X1 : X2;
        u16* dst = Xb + (size_t)z * 2097152;
        int base = (x * 256 + tid) * 8;
        float4 a = *(const float4*)&X[base];
        float4 b = *(const float4*)&X[base + 4];
        ushort4 oa, ob;
        oa.x = f2bf(a.x); oa.y = f2bf(a.y); oa.z = f2bf(a.z); oa.w = f2bf(a.w);
        ob.x = f2bf(b.x); ob.y = f2bf(b.y); ob.z = f2bf(b.z); ob.w = f2bf(b.w);
        *(ushort4*)&dst[base] = oa;
        *(ushort4*)&dst[base + 4] = ob;
    }
}

// ---------------------------------------------------------------------------
// k_qkv_geo: blocks 0..1535 = QKV GEMM (r14 core verbatim, flattened grid);
// blocks 1536..5631 = geo bias (r14 verbatim). Geo overlaps the GEMM wave.
// ---------------------------------------------------------------------------
__global__ __launch_bounds__(256) void k_qkv_geo(const u16* __restrict__ Xb,
                                                 const u16* __restrict__ Wtb,
                                                 const float* __restrict__ bq,
                                                 const float* __restrict__ bk,
                                                 const float* __restrict__ bv,
                                                 u16* __restrict__ qkv,
                                                 const float* __restrict__ box,
                                                 const float* __restrict__ Wg,
                                                 const float* __restrict__ bg,
                                                 u16* __restrict__ Sg) {
    __shared__ __align__(16) unsigned char smem[36864];
    const int tid = threadIdx.x;
    const int bid = blockIdx.x;
    if (bid < 1536) {
        // ---------------- GEMM part (r14 k_gemm_qkv, flattened) ----------------
        u16* As = (u16*)smem;                 // [2][64][72]
        u16* Bs = (u16*)(smem + 18432);       // [2][64][72]
        const int z = bid >> 9, t = bid & 511;
        const int n0 = (t & 7) * 64, m0 = (t >> 3) * 64;
        const u16* Ab = Xb + (size_t)z * 2097152;
        const u16* Wt = Wtb + (size_t)z * 262144;
        const float* bias = (z == 0) ? bq : (z == 1) ? bk : bv;
        u16* dst = qkv + (size_t)z * 2097152;
        const int wid = tid >> 6, lane = tid & 63;
        const int wm = (wid & 1) * 32, wn = (wid >> 1) * 32;
        const int lr = lane & 15, lk8 = (lane >> 4) * 8, quad4 = (lane >> 4) * 4;

        f32x4 acc[2][2];
#pragma unroll
        for (int mi = 0; mi < 2; ++mi)
#pragma unroll
            for (int ni = 0; ni < 2; ++ni) acc[mi][ni] = (f32x4){0.f, 0.f, 0.f, 0.f};

        ushort4 ra[4], rb[4];
#pragma unroll
        for (int r = 0; r < 4; ++r) {
            int p = r * 256 + tid, row = p >> 4, c4 = (p & 15) * 4;
            ra[r] = *(const ushort4*)&Ab[(size_t)(m0 + row) * 512 + c4];
            rb[r] = *(const ushort4*)&Wt[(size_t)(n0 + row) * 512 + c4];
        }
#pragma unroll
        for (int r = 0; r < 4; ++r) {
            int p = r * 256 + tid, row = p >> 4, c4 = (p & 15) * 4;
            *(ushort4*)&As[(0 * 64 + row) * 72 + c4] = ra[r];
            *(ushort4*)&Bs[(0 * 64 + row) * 72 + c4] = rb[r];
        }
        __syncthreads();
        for (int it = 0; it < 8; ++it) {
            const int cur = it & 1;
            if (it < 7) {
                int k0n = (it + 1) * 64;
#pragma unroll
                for (int r = 0; r < 4; ++r) {
                    int p = r * 256 + tid, row = p >> 4, c4 = (p & 15) * 4;
                    ra[r] = *(const ushort4*)&Ab[(size_t)(m0 + row) * 512 + k0n + c4];
                    rb[r] = *(const ushort4*)&Wt[(size_t)(n0 + row) * 512 + k0n + c4];
                }
            }
#pragma unroll
            for (int ks = 0; ks < 64; ks += 32) {
                bf16x8 af[2], bfx[2];
#pragma unroll
                for (int mi = 0; mi < 2; ++mi)
                    af[mi] = *(const bf16x8*)&As[(cur * 64 + wm + mi * 16 + lr) * 72 + ks + lk8];
#pragma unroll
                for (int ni = 0; ni < 2; ++ni)
                    bfx[ni] = *(const bf16x8*)&Bs[(cur * 64 + wn + ni * 16 + lr) * 72 + ks + lk8];
#pragma unroll
                for (int mi = 0; mi < 2; ++mi)
#pragma unroll
                    for (int ni = 0; ni < 2; ++ni)
                        acc[mi][ni] = __builtin_amdgcn_mfma_f32_16x16x32_bf16(
                            af[mi], bfx[ni], acc[mi][ni], 0, 0, 0);
            }
            if (it < 7) {
                const int nxt = 1 - cur;
#pragma unroll
                for (int r = 0; r < 4; ++r) {
                    int p = r * 256 + tid, row = p >> 4, c4 = (p & 15) * 4;
                    *(ushort4*)&As[(nxt * 64 + row) * 72 + c4] = ra[r];
                    *(ushort4*)&Bs[(nxt * 64 + row) * 72 + c4] = rb[r];
                }
                __syncthreads();
            }
        }
        // ---- epilogue via LDS bounce ----
        u16* bounce = (u16*)smem;
        const float scale = (z == 0) ? 0.125f : 1.0f;
        const int h = n0 >> 6, b = m0 >> 8, rrb = m0 & 255;
        __syncthreads();
        if (z == 2) {
#pragma unroll
            for (int mi = 0; mi < 2; ++mi)
#pragma unroll
                for (int ni = 0; ni < 2; ++ni) {
                    int cn = wn + ni * 16 + lr;
                    float bb = bias[n0 + cn];
#pragma unroll
                    for (int reg = 0; reg < 4; ++reg) {
                        int rm = wm + mi * 16 + quad4 + reg;
                        bounce[cn * 72 + rm] = f2bf(acc[mi][ni][reg] + bb);
                    }
                }
            __syncthreads();
#pragma unroll
            for (int r = 0; r < 4; ++r) {
                int p = r * 256 + tid, dn = p >> 4, c4 = (p & 15) * 4;
                *(ushort4*)&dst[(((size_t)(b * H_ + h) * DK_) + dn) * N_ + rrb + c4] =
                    *(const ushort4*)&bounce[dn * 72 + c4];
            }
        } else {
#pragma unroll
            for (int mi = 0; mi < 2; ++mi)
#pragma unroll
                for (int ni = 0; ni < 2; ++ni) {
                    int cn = wn + ni * 16 + lr;
                    float bb = bias[n0 + cn];
#pragma unroll
                    for (int reg = 0; reg < 4; ++reg) {
                        int rm = wm + mi * 16 + quad4 + reg;
                        bounce[rm * 72 + cn] = f2bf((acc[mi][ni][reg] + bb) * scale);
                    }
                }
            __syncthreads();
#pragma unroll
            for (int r = 0; r < 4; ++r) {
                int p = r * 256 + tid, rm = p >> 4, c4 = (p & 15) * 4;
                *(ushort4*)&dst[(((size_t)(b * H_ + h) * N_) + rrb + rm) * DK_ + c4] =
                    *(const ushort4*)&bounce[rm * 72 + c4];
            }
        }
    } else {
        // ---------------- geo part (r14 verbatim) ----------------
        float* sWg = (float*)smem;            // [8][64]
        float* sbg = (float*)(smem + 2048);   // [8]
        if (tid < 8) sbg[tid] = bg[tid];
        { int e = tid; sWg[(e >> 6) * 64 + (e & 63)] = Wg[e];
          e = tid + 256; sWg[(e >> 6) * 64 + (e & 63)] = Wg[e]; }
        const int bi = bid - 1536, b = bi >> 8;
        float4 bxi = *(const float4*)&box[(size_t)bi * 4];
        float4 bxj = *(const float4*)&box[(size_t)(b * N_ + tid) * 4];
        __syncthreads();
        float cxi = (bxi.x + bxi.z) * 0.5f, cyi = (bxi.y + bxi.w) * 0.5f;
        float wi = bxi.z - bxi.x + 1.0f, hi = bxi.w - bxi.y + 1.0f;
        float cxj = (bxj.x + bxj.z) * 0.5f, cyj = (bxj.y + bxj.w) * 0.5f;
        float wj = bxj.z - bxj.x + 1.0f, hj = bxj.w - bxj.y + 1.0f;
        float pos[4];
        pos[0] = __logf(fmaxf(fabsf((cxi - cxj) / wi), 1e-3f));
        pos[1] = __logf(fmaxf(fabsf((cyi - cyj) / hi), 1e-3f));
        pos[2] = __logf(wi / wj);
        pos[3] = __logf(hi / hj);
        const float dm[8] = {1.0f, 0.42169650342858224f, 0.1778279410038923f,
                             0.07498942093324559f, 0.03162277660168379f,
                             0.013335214321633241f, 0.005623413251903491f,
                             0.0023713737056616554f};
        const float inv2pi = 0.15915494309189535f;
        float acc[8];
#pragma unroll
        for (int h = 0; h < 8; ++h) acc[h] = sbg[h];
#pragma unroll
        for (int t = 0; t < 4; ++t) {
            float base = 100.0f * pos[t];
#pragma unroll
            for (int f = 0; f < 8; ++f) {
                float rev = base * dm[f] * inv2pi;
                rev = rev - floorf(rev);
                float sn = __builtin_amdgcn_sinf(rev);
                float cs = __builtin_amdgcn_cosf(rev);
                int idx = t * 8 + f;
#pragma unroll
                for (int h = 0; h < 8; ++h)
                    acc[h] += sWg[h * 64 + idx] * sn + sWg[h * 64 + idx + 32] * cs;
            }
        }
        const int i = bi & 255;
#pragma unroll
        for (int h = 0; h < 8; ++h)
            Sg[(((size_t)(b * H_ + h) * N_) + i) * N_ + tid] =
                f2bf(__logf(fmaxf(acc[h], 1e-6f)));
    }
}

// ---------------------------------------------------------------------------
// k_gemm_out: dbuf core; out(f32) = attnb(bf16) @ Wot^T + bo. (r14 verbatim)
// ---------------------------------------------------------------------------
__global__ __launch_bounds__(256) void k_gemm_out(const u16* __restrict__ Ab,
                                                  const u16* __restrict__ Wt,
                                                  const float* __restrict__ bias,
                                                  float* __restrict__ outp) {
    __shared__ u16 As[2][64][72];
    __shared__ u16 Bs[2][64][72];
    const int tid = threadIdx.x;
    const int n0 = blockIdx.x * 64, m0 = blockIdx.y * 64;
    const int wid = tid >> 6, lane = tid & 63;
    const int wm = (wid & 1) * 32, wn = (wid >> 1) * 32;
    const int lr = lane & 15, lk8 = (lane >> 4) * 8;
    f32x4 acc[2][2];
#pragma unroll
    for (int mi = 0; mi < 2; ++mi)
#pragma unroll
        for (int ni = 0; ni < 2; ++ni) acc[mi][ni] = (f32x4){0.f, 0.f, 0.f, 0.f};
    ushort4 ra[4], rb[4];
#pragma unroll
    for (int r = 0; r < 4; ++r) {
        int p = r * 256 + tid, row = p >> 4, c4 = (p & 15) * 4;
        ra[r] = *(const ushort4*)&Ab[(size_t)(m0 + row) * 512 + c4];
        rb[r] = *(const ushort4*)&Wt[(size_t)(n0 + row) * 512 + c4];
    }
#pragma unroll
    for (int r = 0; r < 4; ++r) {
        int p = r * 256 + tid, row = p >> 4, c4 = (p & 15) * 4;
        *(ushort4*)&As[0][row][c4] = ra[r];
        *(ushort4*)&Bs[0][row][c4] = rb[r];
    }
    __syncthreads();
    for (int it = 0; it < 8; ++it) {
        const int cur = it & 1;
        if (it < 7) {
            int k0n = (it + 1) * 64;
#pragma unroll
            for (int r = 0; r < 4; ++r) {
                int p = r * 256 + tid, row = p >> 4, c4 = (p & 15) * 4;
                ra[r] = *(const ushort4*)&Ab[(size_t)(m0 + row) * 512 + k0n + c4];
                rb[r] = *(const ushort4*)&Wt[(size_t)(n0 + row) * 512 + k0n + c4];
            }
        }
#pragma unroll
        for (int ks = 0; ks < 64; ks += 32) {
            bf16x8 af[2], bfx[2];
#pragma unroll
            for (int mi = 0; mi < 2; ++mi)
                af[mi] = *(const bf16x8*)&As[cur][wm + mi * 16 + lr][ks + lk8];
#pragma unroll
            for (int ni = 0; ni < 2; ++ni)
                bfx[ni] = *(const bf16x8*)&Bs[cur][wn + ni * 16 + lr][ks + lk8];
#pragma unroll
            for (int mi = 0; mi < 2; ++mi)
#pragma unroll
                for (int ni = 0; ni < 2; ++ni)
                    acc[mi][ni] = __builtin_amdgcn_mfma_f32_16x16x32_bf16(
                        af[mi], bfx[ni], acc[mi][ni], 0, 0, 0);
        }
        if (it < 7) {
#pragma unroll
            for (int r = 0; r < 4; ++r) {
                int p = r * 256 + tid, row = p >> 4, c4 = (p & 15) * 4;
                *(ushort4*)&As[1 - cur][row][c4] = ra[r];
                *(ushort4*)&Bs[1 - cur][row][c4] = rb[r];
            }
            __syncthreads();
        }
    }
#pragma unroll
    for (int mi = 0; mi < 2; ++mi)
#pragma unroll
        for (int ni = 0; ni < 2; ++ni) {
            int col = n0 + wn + ni * 16 + lr;
            float bb = bias[col];
#pragma unroll
            for (int reg = 0; reg < 4; ++reg) {
                int m = m0 + wm + mi * 16 + (lane >> 4) * 4 + reg;
                outp[(size_t)m * 512 + col] = acc[mi][ni][reg] + bb;
            }
        }
}

// ---------------------------------------------------------------------------
// k_attn v3 (unchanged from round 11/14).
// ---------------------------------------------------------------------------
__global__ __launch_bounds__(256) void k_attn(const u16* __restrict__ qh,
                                              const u16* __restrict__ kh,
                                              const u16* __restrict__ vhT,
                                              const u16* __restrict__ Sg,
                                              u16* __restrict__ attnb) {
    __shared__ __align__(16) unsigned char smem[40960];
    u16* sQ = (u16*)smem;
    u16* sP = (u16*)(smem + 4608);
    u16* sK = (u16*)(smem + 21504);
    u16* sVt = (u16*)(smem + 21504);
    float* sRedM = (float*)(smem + 39936);
    float* sRedS = (float*)(smem + 40448);

    const int tid = threadIdx.x;
    const int i0 = blockIdx.x * 32;
    const int bh = blockIdx.y;
    const int b = bh >> 3, h = bh & 7;
    const int wid = tid >> 6, lane = tid & 63;
    const int lr = lane & 15, lk8 = (lane >> 4) * 8, quad4 = (lane >> 4) * 4;

#pragma unroll
    for (int r = 0; r < 2; ++r) {
        int p = r * 256 + tid, i = p >> 4, d0 = (p & 15) * 4;
        *(ushort4*)&sQ[i * 72 + d0] =
            *(const ushort4*)&qh[((size_t)bh * N_ + i0 + i) * DK_ + d0];
    }
#pragma unroll
    for (int r = 0; r < 8; ++r) {
        int p = r * 256 + tid, row = p >> 6, jc = (p & 63) * 4;
        *(ushort4*)&sP[row * 264 + jc] =
            *(const ushort4*)&Sg[(((size_t)bh * N_) + i0 + row) * N_ + jc];
    }
#pragma unroll
    for (int r = 0; r < 8; ++r) {
        int p = r * 256 + tid, j = p >> 4, d0 = (p & 15) * 4;
        *(ushort4*)&sK[j * 72 + d0] =
            *(const ushort4*)&kh[((size_t)bh * N_ + j) * DK_ + d0];
    }
    __syncthreads();

    ushort4 kpre[8];
#pragma unroll
    for (int r = 0; r < 8; ++r) {
        int p = r * 256 + tid, j = p >> 4, d0 = (p & 15) * 4;
        kpre[r] = *(const ushort4*)&kh[((size_t)bh * N_ + 128 + j) * DK_ + d0];
    }
    f32x4 acc[2][2][2];
#pragma unroll
    for (int c = 0; c < 2; ++c)
#pragma unroll
        for (int mi = 0; mi < 2; ++mi)
#pragma unroll
            for (int ni = 0; ni < 2; ++ni) acc[c][mi][ni] = (f32x4){0.f, 0.f, 0.f, 0.f};
#pragma unroll
    for (int ks = 0; ks < 64; ks += 32) {
        bf16x8 af[2], bfx[2];
#pragma unroll
        for (int mi = 0; mi < 2; ++mi)
            af[mi] = *(const bf16x8*)&sQ[(mi * 16 + lr) * 72 + ks + lk8];
#pragma unroll
        for (int ni = 0; ni < 2; ++ni)
            bfx[ni] = *(const bf16x8*)&sK[(wid * 32 + ni * 16 + lr) * 72 + ks + lk8];
#pragma unroll
        for (int mi = 0; mi < 2; ++mi)
#pragma unroll
            for (int ni = 0; ni < 2; ++ni)
                acc[0][mi][ni] = __builtin_amdgcn_mfma_f32_16x16x32_bf16(
                    af[mi], bfx[ni], acc[0][mi][ni], 0, 0, 0);
    }
    __syncthreads();
#pragma unroll
    for (int r = 0; r < 8; ++r) {
        int p = r * 256 + tid, j = p >> 4, d0 = (p & 15) * 4;
        *(ushort4*)&sK[j * 72 + d0] = kpre[r];
    }
    __syncthreads();
#pragma unroll
    for (int ks = 0; ks < 64; ks += 32) {
        bf16x8 af[2], bfx[2];
#pragma unroll
        for (int mi = 0; mi < 2; ++mi)
            af[mi] = *(const bf16x8*)&sQ[(mi * 16 + lr) * 72 + ks + lk8];
#pragma unroll
        for (int ni = 0; ni < 2; ++ni)
            bfx[ni] = *(const bf16x8*)&sK[(wid * 32 + ni * 16 + lr) * 72 + ks + lk8];
#pragma unroll
        for (int mi = 0; mi < 2; ++mi)
#pragma unroll
            for (int ni = 0; ni < 2; ++ni)
                acc[1][mi][ni] = __builtin_amdgcn_mfma_f32_16x16x32_bf16(
                    af[mi], bfx[ni], acc[1][mi][ni], 0, 0, 0);
    }
    __syncthreads();

#pragma unroll
    for (int r = 0; r < 8; ++r) {
        int p = r * 256 + tid, d = p >> 5, jc = (p & 31) * 4;
        *(ushort4*)&sVt[d * 136 + jc] =
            *(const ushort4*)&vhT[(((size_t)bh * DK_) + d) * N_ + jc];
    }
#pragma unroll
    for (int c = 0; c < 2; ++c)
#pragma unroll
        for (int mi = 0; mi < 2; ++mi)
#pragma unroll
            for (int ni = 0; ni < 2; ++ni) {
                int col = c * 128 + wid * 32 + ni * 16 + lr;
#pragma unroll
                for (int reg = 0; reg < 4; ++reg) {
                    int row = mi * 16 + quad4 + reg;
                    acc[c][mi][ni][reg] += bf2f(sP[row * 264 + col]);
                }
            }
    float mrow[2][4];
#pragma unroll
    for (int mi = 0; mi < 2; ++mi)
#pragma unroll
        for (int reg = 0; reg < 4; ++reg) {
            float m = acc[0][mi][0][reg];
            m = fmaxf(m, acc[0][mi][1][reg]);
            m = fmaxf(m, acc[1][mi][0][reg]);
            m = fmaxf(m, acc[1][mi][1][reg]);
#pragma unroll
            for (int off = 1; off <= 8; off <<= 1) m = fmaxf(m, __shfl_xor(m, off, 64));
            mrow[mi][reg] = m;
        }
    if (lr == 0) {
#pragma unroll
        for (int mi = 0; mi < 2; ++mi)
#pragma unroll
            for (int reg = 0; reg < 4; ++reg)
                sRedM[(mi * 16 + quad4 + reg) * 4 + wid] = mrow[mi][reg];
    }
    __syncthreads();
    float gm[2][4], sl[2][4];
#pragma unroll
    for (int mi = 0; mi < 2; ++mi)
#pragma unroll
        for (int reg = 0; reg < 4; ++reg) {
            float4 mm = *(const float4*)&sRedM[(mi * 16 + quad4 + reg) * 4];
            gm[mi][reg] = fmaxf(fmaxf(mm.x, mm.y), fmaxf(mm.z, mm.w));
            sl[mi][reg] = 0.f;
        }
#pragma unroll
    for (int c = 0; c < 2; ++c)
#pragma unroll
        for (int mi = 0; mi < 2; ++mi)
#pragma unroll
            for (int ni = 0; ni < 2; ++ni)
#pragma unroll
                for (int reg = 0; reg < 4; ++reg) {
                    float e = __expf(acc[c][mi][ni][reg] - gm[mi][reg]);
                    acc[c][mi][ni][reg] = e;
                    sl[mi][reg] += e;
                }
#pragma unroll
    for (int mi = 0; mi < 2; ++mi)
#pragma unroll
        for (int reg = 0; reg < 4; ++reg) {
            float s = sl[mi][reg];
#pragma unroll
            for (int off = 1; off <= 8; off <<= 1) s += __shfl_xor(s, off, 64);
            sl[mi][reg] = s;
        }
    if (lr == 0) {
#pragma unroll
        for (int mi = 0; mi < 2; ++mi)
#pragma unroll
            for (int reg = 0; reg < 4; ++reg)
                sRedS[(mi * 16 + quad4 + reg) * 4 + wid] = sl[mi][reg];
    }
    __syncthreads();
#pragma unroll
    for (int mi = 0; mi < 2; ++mi)
#pragma unroll
        for (int reg = 0; reg < 4; ++reg) {
            float4 ss = *(const float4*)&sRedS[(mi * 16 + quad4 + reg) * 4];
            gm[mi][reg] = 1.0f / (ss.x + ss.y + ss.z + ss.w);
        }
#pragma unroll
    for (int c = 0; c < 2; ++c)
#pragma unroll
        for (int mi = 0; mi < 2; ++mi)
#pragma unroll
            for (int ni = 0; ni < 2; ++ni) {
                int col = c * 128 + wid * 32 + ni * 16 + lr;
#pragma unroll
                for (int reg = 0; reg < 4; ++reg) {
                    int row = mi * 16 + quad4 + reg;
                    sP[row * 264 + col] = f2bf(acc[c][mi][ni][reg] * gm[mi][reg]);
                }
            }
    __syncthreads();

    f32x4 o[2];
    o[0] = (f32x4){0.f, 0.f, 0.f, 0.f};
    o[1] = (f32x4){0.f, 0.f, 0.f, 0.f};
#pragma unroll
    for (int k0 = 0; k0 < 128; k0 += 32) {
        bf16x8 bfx = *(const bf16x8*)&sVt[(wid * 16 + lr) * 136 + k0 + lk8];
#pragma unroll
        for (int mi = 0; mi < 2; ++mi) {
            bf16x8 af = *(const bf16x8*)&sP[(mi * 16 + lr) * 264 + k0 + lk8];
            o[mi] = __builtin_amdgcn_mfma_f32_16x16x32_bf16(af, bfx, o[mi], 0, 0, 0);
        }
    }
    __syncthreads();
#pragma unroll
    for (int r = 0; r < 8; ++r) {
        int p = r * 256 + tid, d = p >> 5, jc = (p & 31) * 4;
        *(ushort4*)&sVt[d * 136 + jc] =
            *(const ushort4*)&vhT[(((size_t)bh * DK_) + d) * N_ + 128 + jc];
    }
    __syncthreads();
#pragma unroll
    for (int k0 = 0; k0 < 128; k0 += 32) {
        bf16x8 bfx = *(const bf16x8*)&sVt[(wid * 16 + lr) * 136 + k0 + lk8];
#pragma unroll
        for (int mi = 0; mi < 2; ++mi) {
            bf16x8 af = *(const bf16x8*)&sP[(mi * 16 + lr) * 264 + 128 + k0 + lk8];
            o[mi] = __builtin_amdgcn_mfma_f32_16x16x32_bf16(af, bfx, o[mi], 0, 0, 0);
        }
    }
#pragma unroll
    for (int mi = 0; mi < 2; ++mi)
#pragma unroll
        for (int reg = 0; reg < 4; ++reg) {
            int row = mi * 16 + quad4 + reg;
            attnb[((size_t)(b * N_ + i0 + row)) * D_ + h * 64 + wid * 16 + lr] =
                f2bf(o[mi][reg]);
        }
}

extern "C" void kernel_launch(void* const* d_in, const int* in_sizes, int n_in,
                              void* d_out, int out_size, void* d_ws, size_t ws_size,
                              hipStream_t stream) {
    const float* Xq = (const float*)d_in[0];
    const float* Xk = (const float*)d_in[1];
    const float* Xv = (const float*)d_in[2];
    const float* box = (const float*)d_in[3];
    const float* Wq = (const float*)d_in[4];
    const float* bq = (const float*)d_in[5];
    const float* Wk = (const float*)d_in[6];
    const float* bk = (const float*)d_in[7];
    const float* Wv = (const float*)d_in[8];
    const float* bv = (const float*)d_in[9];
    const float* Wo = (const float*)d_in[10];
    const float* bo = (const float*)d_in[11];
    const float* Wg = (const float*)d_in[12];
    const float* bg = (const float*)d_in[13];
    float* out = (float*)d_out;

    // ws (u16 units): [0,6M) qkv | [6M,14.39M) Sg | [14M,16M) attnb |
    // [16M,17.05M) Wt | [18M,24.3M) Xb.
    u16* ws16 = (u16*)d_ws;
    u16* qkv = ws16;
    u16* qh = qkv;
    u16* kh = qkv + 2097152;
    u16* vhT = qkv + 4194304;
    u16* Sg = ws16 + 6291456;
    u16* attnb = ws16 + 14680064;
    u16* Wt = ws16 + 16777216;
    u16* Xb = ws16 + 18874368;

    dim3 blk(256);
    k_prep_lite<<<dim3(4096), blk, 0, stream>>>(Wq, Wk, Wv, Wo, Wt, Xq, Xk, Xv, Xb);
    k_qkv_geo<<<dim3(5632), blk, 0, stream>>>(Xb, Wt, bq, bk, bv, qkv,
                                              box, Wg, bg, Sg);
    k_attn<<<dim3(8, 128), blk, 0, stream>>>(qh, kh, vhT, Sg, attnb);
    k_gemm_out<<<dim3(8, 64), blk, 0, stream>>>(attnb, Wo == nullptr ? nullptr : Wt + 3 * 262144, bo, out);
}

// Round 16
// 163.091 us; speedup vs baseline: 1.0529x; 1.0529x over previous
//
#include <hip/hip_runtime.h>
#include <hip/hip_bf16.h>

#define B_ 16
#define N_ 256
#define D_ 512
#define H_ 8
#define DK_ 64

typedef unsigned short u16;
typedef __attribute__((ext_vector_type(8))) short bf16x8;
typedef __attribute__((ext_vector_type(4))) float f32x4;

__device__ __forceinline__ float bf2f(u16 u) {
    union { unsigned int i; float f; } v;
    v.i = ((unsigned int)u) << 16;
    return v.f;
}
__device__ __forceinline__ u16 f2bf(float f) {
    union { float f; unsigned int i; } v;
    v.f = f;
    unsigned int x = v.i;
    unsigned int r = (x >> 16) & 1u;
    x += 0x7fffu + r;           // round-to-nearest-even
    return (u16)(x >> 16);
}

// ---------------------------------------------------------------------------
// k_prep: blocks 0..4095 geo | 4096..5119 wtrans | 5120..8191 X->bf16 cvt.
// (r14 verbatim)
// ---------------------------------------------------------------------------
__global__ __launch_bounds__(256) void k_prep(const float* __restrict__ box,
                                              const float* __restrict__ Wg,
                                              const float* __restrict__ bg,
                                              u16* __restrict__ Sg,
                                              const float* __restrict__ W0,
                                              const float* __restrict__ W1,
                                              const float* __restrict__ W2,
                                              const float* __restrict__ W3,
                                              u16* __restrict__ Wt,
                                              const float* __restrict__ X0,
                                              const float* __restrict__ X1,
                                              const float* __restrict__ X2,
                                              u16* __restrict__ Xb) {
    const int tid = threadIdx.x;
    const int bid = blockIdx.x;
    if (bid < 4096) {
        __shared__ float sWg[8][64];
        __shared__ float sbg[8];
        if (tid < 8) sbg[tid] = bg[tid];
        { int e = tid; sWg[e >> 6][e & 63] = Wg[e];
          e = tid + 256; sWg[e >> 6][e & 63] = Wg[e]; }
        const int bi = bid, b = bi >> 8;
        float4 bxi = *(const float4*)&box[(size_t)bi * 4];
        float4 bxj = *(const float4*)&box[(size_t)(b * N_ + tid) * 4];
        __syncthreads();
        float cxi = (bxi.x + bxi.z) * 0.5f, cyi = (bxi.y + bxi.w) * 0.5f;
        float wi = bxi.z - bxi.x + 1.0f, hi = bxi.w - bxi.y + 1.0f;
        float cxj = (bxj.x + bxj.z) * 0.5f, cyj = (bxj.y + bxj.w) * 0.5f;
        float wj = bxj.z - bxj.x + 1.0f, hj = bxj.w - bxj.y + 1.0f;
        float pos[4];
        pos[0] = __logf(fmaxf(fabsf((cxi - cxj) / wi), 1e-3f));
        pos[1] = __logf(fmaxf(fabsf((cyi - cyj) / hi), 1e-3f));
        pos[2] = __logf(wi / wj);
        pos[3] = __logf(hi / hj);
        const float dm[8] = {1.0f, 0.42169650342858224f, 0.1778279410038923f,
                             0.07498942093324559f, 0.03162277660168379f,
                             0.013335214321633241f, 0.005623413251903491f,
                             0.0023713737056616554f};
        const float inv2pi = 0.15915494309189535f;
        float acc[8];
#pragma unroll
        for (int h = 0; h < 8; ++h) acc[h] = sbg[h];
#pragma unroll
        for (int t = 0; t < 4; ++t) {
            float base = 100.0f * pos[t];
#pragma unroll
            for (int f = 0; f < 8; ++f) {
                float rev = base * dm[f] * inv2pi;
                rev = rev - floorf(rev);
                float sn = __builtin_amdgcn_sinf(rev);
                float cs = __builtin_amdgcn_cosf(rev);
                int idx = t * 8 + f;
#pragma unroll
                for (int h = 0; h < 8; ++h)
                    acc[h] += sWg[h][idx] * sn + sWg[h][idx + 32] * cs;
            }
        }
        const int i = bi & 255;
#pragma unroll
        for (int h = 0; h < 8; ++h)
            Sg[(((size_t)(b * H_ + h) * N_) + i) * N_ + tid] =
                f2bf(__logf(fmaxf(acc[h], 1e-6f)));
    } else if (bid < 5120) {
        __shared__ float tt[32][33];
        int t = bid - 4096;
        int z = t >> 8, yb = (t >> 4) & 15, xb = t & 15;
        const float* W = (z == 0) ? W0 : (z == 1) ? W1 : (z == 2) ? W2 : W3;
        u16* dst = Wt + (size_t)z * 262144;
        const int kb = yb * 32, nb = xb * 32;
#pragma unroll
        for (int r = 0; r < 4; ++r) {
            int p = r * 256 + tid;
            tt[p >> 5][p & 31] = W[(size_t)(kb + (p >> 5)) * 512 + nb + (p & 31)];
        }
        __syncthreads();
#pragma unroll
        for (int r = 0; r < 4; ++r) {
            int p = r * 256 + tid;
            dst[(size_t)(nb + (p >> 5)) * 512 + kb + (p & 31)] = f2bf(tt[p & 31][p >> 5]);
        }
    } else {
        int t = bid - 5120;
        int z = t >> 10, x = t & 1023;
        const float* X = (z == 0) ? X0 : (z == 1) ? X1 : X2;
        u16* dst = Xb + (size_t)z * 2097152;
        int base = (x * 256 + tid) * 8;
        float4 a = *(const float4*)&X[base];
        float4 b = *(const float4*)&X[base + 4];
        ushort4 oa, ob;
        oa.x = f2bf(a.x); oa.y = f2bf(a.y); oa.z = f2bf(a.z); oa.w = f2bf(a.w);
        ob.x = f2bf(b.x); ob.y = f2bf(b.y); ob.z = f2bf(b.z); ob.w = f2bf(b.w);
        *(ushort4*)&dst[base] = oa;
        *(ushort4*)&dst[base + 4] = ob;
    }
}

// ---------------------------------------------------------------------------
// k_gemm_qkv: r14 core; grid (64,8,3) so linear id % 8 == m-tile % 8 ->
// all 8 n-blocks of an m-tile share one XCD (A-tile fetched once per XCD).
// ---------------------------------------------------------------------------
__global__ __launch_bounds__(256) void k_gemm_qkv(const u16* __restrict__ Xb,
                                                  const u16* __restrict__ Wtb,
                                                  const float* __restrict__ bq,
                                                  const float* __restrict__ bk,
                                                  const float* __restrict__ bv,
                                                  u16* __restrict__ qkv) {
    const int z = blockIdx.z;
    const u16* Ab = Xb + (size_t)z * 2097152;
    const u16* Wt = Wtb + (size_t)z * 262144;
    const float* bias = (z == 0) ? bq : (z == 1) ? bk : bv;
    u16* dst = qkv + (size_t)z * 2097152;

    __shared__ u16 As[2][64][72];
    __shared__ u16 Bs[2][64][72];
    const int tid = threadIdx.x;
    const int m0 = blockIdx.x * 64, n0 = blockIdx.y * 64;   // XCD swizzle: id%8 = m%8
    const int wid = tid >> 6, lane = tid & 63;
    const int wm = (wid & 1) * 32, wn = (wid >> 1) * 32;
    const int lr = lane & 15, lk8 = (lane >> 4) * 8, quad4 = (lane >> 4) * 4;

    f32x4 acc[2][2];
#pragma unroll
    for (int mi = 0; mi < 2; ++mi)
#pragma unroll
        for (int ni = 0; ni < 2; ++ni) acc[mi][ni] = (f32x4){0.f, 0.f, 0.f, 0.f};

    ushort4 ra[4], rb[4];
#pragma unroll
    for (int r = 0; r < 4; ++r) {
        int p = r * 256 + tid, row = p >> 4, c4 = (p & 15) * 4;
        ra[r] = *(const ushort4*)&Ab[(size_t)(m0 + row) * 512 + c4];
        rb[r] = *(const ushort4*)&Wt[(size_t)(n0 + row) * 512 + c4];
    }
#pragma unroll
    for (int r = 0; r < 4; ++r) {
        int p = r * 256 + tid, row = p >> 4, c4 = (p & 15) * 4;
        *(ushort4*)&As[0][row][c4] = ra[r];
        *(ushort4*)&Bs[0][row][c4] = rb[r];
    }
    __syncthreads();
    for (int it = 0; it < 8; ++it) {
        const int cur = it & 1;
        if (it < 7) {
            int k0n = (it + 1) * 64;
#pragma unroll
            for (int r = 0; r < 4; ++r) {
                int p = r * 256 + tid, row = p >> 4, c4 = (p & 15) * 4;
                ra[r] = *(const ushort4*)&Ab[(size_t)(m0 + row) * 512 + k0n + c4];
                rb[r] = *(const ushort4*)&Wt[(size_t)(n0 + row) * 512 + k0n + c4];
            }
        }
#pragma unroll
        for (int ks = 0; ks < 64; ks += 32) {
            bf16x8 af[2], bfx[2];
#pragma unroll
            for (int mi = 0; mi < 2; ++mi)
                af[mi] = *(const bf16x8*)&As[cur][wm + mi * 16 + lr][ks + lk8];
#pragma unroll
            for (int ni = 0; ni < 2; ++ni)
                bfx[ni] = *(const bf16x8*)&Bs[cur][wn + ni * 16 + lr][ks + lk8];
#pragma unroll
            for (int mi = 0; mi < 2; ++mi)
#pragma unroll
                for (int ni = 0; ni < 2; ++ni)
                    acc[mi][ni] = __builtin_amdgcn_mfma_f32_16x16x32_bf16(
                        af[mi], bfx[ni], acc[mi][ni], 0, 0, 0);
        }
        if (it < 7) {
#pragma unroll
            for (int r = 0; r < 4; ++r) {
                int p = r * 256 + tid, row = p >> 4, c4 = (p & 15) * 4;
                *(ushort4*)&As[1 - cur][row][c4] = ra[r];
                *(ushort4*)&Bs[1 - cur][row][c4] = rb[r];
            }
            __syncthreads();
        }
    }
    // ---- epilogue via LDS bounce ----
    u16* bounce = &As[0][0][0];
    const float scale = (z == 0) ? 0.125f : 1.0f;
    const int h = n0 >> 6, b = m0 >> 8, rrb = m0 & 255;
    if (z == 2) {
#pragma unroll
        for (int mi = 0; mi < 2; ++mi)
#pragma unroll
            for (int ni = 0; ni < 2; ++ni) {
                int cn = wn + ni * 16 + lr;
                float bb = bias[n0 + cn];
#pragma unroll
                for (int reg = 0; reg < 4; ++reg) {
                    int rm = wm + mi * 16 + quad4 + reg;
                    bounce[cn * 72 + rm] = f2bf(acc[mi][ni][reg] + bb);
                }
            }
        __syncthreads();
#pragma unroll
        for (int r = 0; r < 4; ++r) {
            int p = r * 256 + tid, dn = p >> 4, c4 = (p & 15) * 4;
            *(ushort4*)&dst[(((size_t)(b * H_ + h) * DK_) + dn) * N_ + rrb + c4] =
                *(const ushort4*)&bounce[dn * 72 + c4];
        }
    } else {
#pragma unroll
        for (int mi = 0; mi < 2; ++mi)
#pragma unroll
            for (int ni = 0; ni < 2; ++ni) {
                int cn = wn + ni * 16 + lr;
                float bb = bias[n0 + cn];
#pragma unroll
                for (int reg = 0; reg < 4; ++reg) {
                    int rm = wm + mi * 16 + quad4 + reg;
                    bounce[rm * 72 + cn] = f2bf((acc[mi][ni][reg] + bb) * scale);
                }
            }
        __syncthreads();
#pragma unroll
        for (int r = 0; r < 4; ++r) {
            int p = r * 256 + tid, rm = p >> 4, c4 = (p & 15) * 4;
            *(ushort4*)&dst[(((size_t)(b * H_ + h) * N_) + rrb + rm) * DK_ + c4] =
                *(const ushort4*)&bounce[rm * 72 + c4];
        }
    }
}

// ---------------------------------------------------------------------------
// k_gemm_out: r14 core; grid (64,8) -> id%8 = m%8 (attnb tile fetched once/XCD).
// ---------------------------------------------------------------------------
__global__ __launch_bounds__(256) void k_gemm_out(const u16* __restrict__ Ab,
                                                  const u16* __restrict__ Wt,
                                                  const float* __restrict__ bias,
                                                  float* __restrict__ outp) {
    __shared__ u16 As[2][64][72];
    __shared__ u16 Bs[2][64][72];
    const int tid = threadIdx.x;
    const int m0 = blockIdx.x * 64, n0 = blockIdx.y * 64;   // XCD swizzle
    const int wid = tid >> 6, lane = tid & 63;
    const int wm = (wid & 1) * 32, wn = (wid >> 1) * 32;
    const int lr = lane & 15, lk8 = (lane >> 4) * 8;
    f32x4 acc[2][2];
#pragma unroll
    for (int mi = 0; mi < 2; ++mi)
#pragma unroll
        for (int ni = 0; ni < 2; ++ni) acc[mi][ni] = (f32x4){0.f, 0.f, 0.f, 0.f};
    ushort4 ra[4], rb[4];
#pragma unroll
    for (int r = 0; r < 4; ++r) {
        int p = r * 256 + tid, row = p >> 4, c4 = (p & 15) * 4;
        ra[r] = *(const ushort4*)&Ab[(size_t)(m0 + row) * 512 + c4];
        rb[r] = *(const ushort4*)&Wt[(size_t)(n0 + row) * 512 + c4];
    }
#pragma unroll
    for (int r = 0; r < 4; ++r) {
        int p = r * 256 + tid, row = p >> 4, c4 = (p & 15) * 4;
        *(ushort4*)&As[0][row][c4] = ra[r];
        *(ushort4*)&Bs[0][row][c4] = rb[r];
    }
    __syncthreads();
    for (int it = 0; it < 8; ++it) {
        const int cur = it & 1;
        if (it < 7) {
            int k0n = (it + 1) * 64;
#pragma unroll
            for (int r = 0; r < 4; ++r) {
                int p = r * 256 + tid, row = p >> 4, c4 = (p & 15) * 4;
                ra[r] = *(const ushort4*)&Ab[(size_t)(m0 + row) * 512 + k0n + c4];
                rb[r] = *(const ushort4*)&Wt[(size_t)(n0 + row) * 512 + k0n + c4];
            }
        }
#pragma unroll
        for (int ks = 0; ks < 64; ks += 32) {
            bf16x8 af[2], bfx[2];
#pragma unroll
            for (int mi = 0; mi < 2; ++mi)
                af[mi] = *(const bf16x8*)&As[cur][wm + mi * 16 + lr][ks + lk8];
#pragma unroll
            for (int ni = 0; ni < 2; ++ni)
                bfx[ni] = *(const bf16x8*)&Bs[cur][wn + ni * 16 + lr][ks + lk8];
#pragma unroll
            for (int mi = 0; mi < 2; ++mi)
#pragma unroll
                for (int ni = 0; ni < 2; ++ni)
                    acc[mi][ni] = __builtin_amdgcn_mfma_f32_16x16x32_bf16(
                        af[mi], bfx[ni], acc[mi][ni], 0, 0, 0);
        }
        if (it < 7) {
#pragma unroll
            for (int r = 0; r < 4; ++r) {
                int p = r * 256 + tid, row = p >> 4, c4 = (p & 15) * 4;
                *(ushort4*)&As[1 - cur][row][c4] = ra[r];
                *(ushort4*)&Bs[1 - cur][row][c4] = rb[r];
            }
            __syncthreads();
        }
    }
#pragma unroll
    for (int mi = 0; mi < 2; ++mi)
#pragma unroll
        for (int ni = 0; ni < 2; ++ni) {
            int col = n0 + wn + ni * 16 + lr;
            float bb = bias[col];
#pragma unroll
            for (int reg = 0; reg < 4; ++reg) {
                int m = m0 + wm + mi * 16 + (lane >> 4) * 4 + reg;
                outp[(size_t)m * 512 + col] = acc[mi][ni][reg] + bb;
            }
        }
}

// ---------------------------------------------------------------------------
// k_attn v3 (r14 core); grid (128,8): x=bh, y=i-tile -> id%8 = bh%8 so the
// 8 i-tiles of one bh share that XCD's K/V/Sg in L2.
// ---------------------------------------------------------------------------
__global__ __launch_bounds__(256) void k_attn(const u16* __restrict__ qh,
                                              const u16* __restrict__ kh,
                                              const u16* __restrict__ vhT,
                                              const u16* __restrict__ Sg,
                                              u16* __restrict__ attnb) {
    __shared__ __align__(16) unsigned char smem[40960];
    u16* sQ = (u16*)smem;
    u16* sP = (u16*)(smem + 4608);
    u16* sK = (u16*)(smem + 21504);
    u16* sVt = (u16*)(smem + 21504);
    float* sRedM = (float*)(smem + 39936);
    float* sRedS = (float*)(smem + 40448);

    const int tid = threadIdx.x;
    const int bh = blockIdx.x;                 // XCD swizzle: id%8 = bh%8
    const int i0 = blockIdx.y * 32;
    const int b = bh >> 3, h = bh & 7;
    const int wid = tid >> 6, lane = tid & 63;
    const int lr = lane & 15, lk8 = (lane >> 4) * 8, quad4 = (lane >> 4) * 4;

#pragma unroll
    for (int r = 0; r < 2; ++r) {
        int p = r * 256 + tid, i = p >> 4, d0 = (p & 15) * 4;
        *(ushort4*)&sQ[i * 72 + d0] =
            *(const ushort4*)&qh[((size_t)bh * N_ + i0 + i) * DK_ + d0];
    }
#pragma unroll
    for (int r = 0; r < 8; ++r) {
        int p = r * 256 + tid, row = p >> 6, jc = (p & 63) * 4;
        *(ushort4*)&sP[row * 264 + jc] =
            *(const ushort4*)&Sg[(((size_t)bh * N_) + i0 + row) * N_ + jc];
    }
#pragma unroll
    for (int r = 0; r < 8; ++r) {
        int p = r * 256 + tid, j = p >> 4, d0 = (p & 15) * 4;
        *(ushort4*)&sK[j * 72 + d0] =
            *(const ushort4*)&kh[((size_t)bh * N_ + j) * DK_ + d0];
    }
    __syncthreads();

    ushort4 kpre[8];
#pragma unroll
    for (int r = 0; r < 8; ++r) {
        int p = r * 256 + tid, j = p >> 4, d0 = (p & 15) * 4;
        kpre[r] = *(const ushort4*)&kh[((size_t)bh * N_ + 128 + j) * DK_ + d0];
    }
    f32x4 acc[2][2][2];
#pragma unroll
    for (int c = 0; c < 2; ++c)
#pragma unroll
        for (int mi = 0; mi < 2; ++mi)
#pragma unroll
            for (int ni = 0; ni < 2; ++ni) acc[c][mi][ni] = (f32x4){0.f, 0.f, 0.f, 0.f};
#pragma unroll
    for (int ks = 0; ks < 64; ks += 32) {
        bf16x8 af[2], bfx[2];
#pragma unroll
        for (int mi = 0; mi < 2; ++mi)
            af[mi] = *(const bf16x8*)&sQ[(mi * 16 + lr) * 72 + ks + lk8];
#pragma unroll
        for (int ni = 0; ni < 2; ++ni)
            bfx[ni] = *(const bf16x8*)&sK[(wid * 32 + ni * 16 + lr) * 72 + ks + lk8];
#pragma unroll
        for (int mi = 0; mi < 2; ++mi)
#pragma unroll
            for (int ni = 0; ni < 2; ++ni)
                acc[0][mi][ni] = __builtin_amdgcn_mfma_f32_16x16x32_bf16(
                    af[mi], bfx[ni], acc[0][mi][ni], 0, 0, 0);
    }
    __syncthreads();
#pragma unroll
    for (int r = 0; r < 8; ++r) {
        int p = r * 256 + tid, j = p >> 4, d0 = (p & 15) * 4;
        *(ushort4*)&sK[j * 72 + d0] = kpre[r];
    }
    __syncthreads();
#pragma unroll
    for (int ks = 0; ks < 64; ks += 32) {
        bf16x8 af[2], bfx[2];
#pragma unroll
        for (int mi = 0; mi < 2; ++mi)
            af[mi] = *(const bf16x8*)&sQ[(mi * 16 + lr) * 72 + ks + lk8];
#pragma unroll
        for (int ni = 0; ni < 2; ++ni)
            bfx[ni] = *(const bf16x8*)&sK[(wid * 32 + ni * 16 + lr) * 72 + ks + lk8];
#pragma unroll
        for (int mi = 0; mi < 2; ++mi)
#pragma unroll
            for (int ni = 0; ni < 2; ++ni)
                acc[1][mi][ni] = __builtin_amdgcn_mfma_f32_16x16x32_bf16(
                    af[mi], bfx[ni], acc[1][mi][ni], 0, 0, 0);
    }
    __syncthreads();

#pragma unroll
    for (int r = 0; r < 8; ++r) {
        int p = r * 256 + tid, d = p >> 5, jc = (p & 31) * 4;
        *(ushort4*)&sVt[d * 136 + jc] =
            *(const ushort4*)&vhT[(((size_t)bh * DK_) + d) * N_ + jc];
    }
#pragma unroll
    for (int c = 0; c < 2; ++c)
#pragma unroll
        for (int mi = 0; mi < 2; ++mi)
#pragma unroll
            for (int ni = 0; ni < 2; ++ni) {
                int col = c * 128 + wid * 32 + ni * 16 + lr;
#pragma unroll
                for (int reg = 0; reg < 4; ++reg) {
                    int row = mi * 16 + quad4 + reg;
                    acc[c][mi][ni][reg] += bf2f(sP[row * 264 + col]);
                }
            }
    float mrow[2][4];
#pragma unroll
    for (int mi = 0; mi < 2; ++mi)
#pragma unroll
        for (int reg = 0; reg < 4; ++reg) {
            float m = acc[0][mi][0][reg];
            m = fmaxf(m, acc[0][mi][1][reg]);
            m = fmaxf(m, acc[1][mi][0][reg]);
            m = fmaxf(m, acc[1][mi][1][reg]);
#pragma unroll
            for (int off = 1; off <= 8; off <<= 1) m = fmaxf(m, __shfl_xor(m, off, 64));
            mrow[mi][reg] = m;
        }
    if (lr == 0) {
#pragma unroll
        for (int mi = 0; mi < 2; ++mi)
#pragma unroll
            for (int reg = 0; reg < 4; ++reg)
                sRedM[(mi * 16 + quad4 + reg) * 4 + wid] = mrow[mi][reg];
    }
    __syncthreads();
    float gm[2][4], sl[2][4];
#pragma unroll
    for (int mi = 0; mi < 2; ++mi)
#pragma unroll
        for (int reg = 0; reg < 4; ++reg) {
            float4 mm = *(const float4*)&sRedM[(mi * 16 + quad4 + reg) * 4];
            gm[mi][reg] = fmaxf(fmaxf(mm.x, mm.y), fmaxf(mm.z, mm.w));
            sl[mi][reg] = 0.f;
        }
#pragma unroll
    for (int c = 0; c < 2; ++c)
#pragma unroll
        for (int mi = 0; mi < 2; ++mi)
#pragma unroll
            for (int ni = 0; ni < 2; ++ni)
#pragma unroll
                for (int reg = 0; reg < 4; ++reg) {
                    float e = __expf(acc[c][mi][ni][reg] - gm[mi][reg]);
                    acc[c][mi][ni][reg] = e;
                    sl[mi][reg] += e;
                }
#pragma unroll
    for (int mi = 0; mi < 2; ++mi)
#pragma unroll
        for (int reg = 0; reg < 4; ++reg) {
            float s = sl[mi][reg];
#pragma unroll
            for (int off = 1; off <= 8; off <<= 1) s += __shfl_xor(s, off, 64);
            sl[mi][reg] = s;
        }
    if (lr == 0) {
#pragma unroll
        for (int mi = 0; mi < 2; ++mi)
#pragma unroll
            for (int reg = 0; reg < 4; ++reg)
                sRedS[(mi * 16 + quad4 + reg) * 4 + wid] = sl[mi][reg];
    }
    __syncthreads();
#pragma unroll
    for (int mi = 0; mi < 2; ++mi)
#pragma unroll
        for (int reg = 0; reg < 4; ++reg) {
            float4 ss = *(const float4*)&sRedS[(mi * 16 + quad4 + reg) * 4];
            gm[mi][reg] = 1.0f / (ss.x + ss.y + ss.z + ss.w);
        }
#pragma unroll
    for (int c = 0; c < 2; ++c)
#pragma unroll
        for (int mi = 0; mi < 2; ++mi)
#pragma unroll
            for (int ni = 0; ni < 2; ++ni) {
                int col = c * 128 + wid * 32 + ni * 16 + lr;
#pragma unroll
                for (int reg = 0; reg < 4; ++reg) {
                    int row = mi * 16 + quad4 + reg;
                    sP[row * 264 + col] = f2bf(acc[c][mi][ni][reg] * gm[mi][reg]);
                }
            }
    __syncthreads();

    f32x4 o[2];
    o[0] = (f32x4){0.f, 0.f, 0.f, 0.f};
    o[1] = (f32x4){0.f, 0.f, 0.f, 0.f};
#pragma unroll
    for (int k0 = 0; k0 < 128; k0 += 32) {
        bf16x8 bfx = *(const bf16x8*)&sVt[(wid * 16 + lr) * 136 + k0 + lk8];
#pragma unroll
        for (int mi = 0; mi < 2; ++mi) {
            bf16x8 af = *(const bf16x8*)&sP[(mi * 16 + lr) * 264 + k0 + lk8];
            o[mi] = __builtin_amdgcn_mfma_f32_16x16x32_bf16(af, bfx, o[mi], 0, 0, 0);
        }
    }
    __syncthreads();
#pragma unroll
    for (int r = 0; r < 8; ++r) {
        int p = r * 256 + tid, d = p >> 5, jc = (p & 31) * 4;
        *(ushort4*)&sVt[d * 136 + jc] =
            *(const ushort4*)&vhT[(((size_t)bh * DK_) + d) * N_ + 128 + jc];
    }
    __syncthreads();
#pragma unroll
    for (int k0 = 0; k0 < 128; k0 += 32) {
        bf16x8 bfx = *(const bf16x8*)&sVt[(wid * 16 + lr) * 136 + k0 + lk8];
#pragma unroll
        for (int mi = 0; mi < 2; ++mi) {
            bf16x8 af = *(const bf16x8*)&sP[(mi * 16 + lr) * 264 + 128 + k0 + lk8];
            o[mi] = __builtin_amdgcn_mfma_f32_16x16x32_bf16(af, bfx, o[mi], 0, 0, 0);
        }
    }
#pragma unroll
    for (int mi = 0; mi < 2; ++mi)
#pragma unroll
        for (int reg = 0; reg < 4; ++reg) {
            int row = mi * 16 + quad4 + reg;
            attnb[((size_t)(b * N_ + i0 + row)) * D_ + h * 64 + wid * 16 + lr] =
                f2bf(o[mi][reg]);
        }
}

extern "C" void kernel_launch(void* const* d_in, const int* in_sizes, int n_in,
                              void* d_out, int out_size, void* d_ws, size_t ws_size,
                              hipStream_t stream) {
    const float* Xq = (const float*)d_in[0];
    const float* Xk = (const float*)d_in[1];
    const float* Xv = (const float*)d_in[2];
    const float* box = (const float*)d_in[3];
    const float* Wq = (const float*)d_in[4];
    const float* bq = (const float*)d_in[5];
    const float* Wk = (const float*)d_in[6];
    const float* bk = (const float*)d_in[7];
    const float* Wv = (const float*)d_in[8];
    const float* bv = (const float*)d_in[9];
    const float* Wo = (const float*)d_in[10];
    const float* bo = (const float*)d_in[11];
    const float* Wg = (const float*)d_in[12];
    const float* bg = (const float*)d_in[13];
    float* out = (float*)d_out;

    // ws (u16 units): [0,6M) qkv | [6M,14.39M) Sg | [14M,16M) attnb |
    // [16M,17.05M) Wt | [18M,24.3M) Xb.
    u16* ws16 = (u16*)d_ws;
    u16* qkv = ws16;
    u16* qh = qkv;
    u16* kh = qkv + 2097152;
    u16* vhT = qkv + 4194304;
    u16* Sg = ws16 + 6291456;
    u16* attnb = ws16 + 14680064;
    u16* Wt = ws16 + 16777216;
    u16* Xb = ws16 + 18874368;

    dim3 blk(256);
    k_prep<<<dim3(8192), blk, 0, stream>>>(box, Wg, bg, Sg, Wq, Wk, Wv, Wo, Wt,
                                           Xq, Xk, Xv, Xb);
    k_gemm_qkv<<<dim3(64, 8, 3), blk, 0, stream>>>(Xb, Wt, bq, bk, bv, qkv);
    k_attn<<<dim3(128, 8), blk, 0, stream>>>(qh, kh, vhT, Sg, attnb);
    k_gemm_out<<<dim3(64, 8), blk, 0, stream>>>(attnb, Wt + 3 * 262144, bo, out);
}

// Round 17
// 161.045 us; speedup vs baseline: 1.0663x; 1.0127x over previous
//
#include <hip/hip_runtime.h>
#include <hip/hip_bf16.h>

#define B_ 16
#define N_ 256
#define D_ 512
#define H_ 8
#define DK_ 64

typedef unsigned short u16;
typedef __attribute__((ext_vector_type(8))) short bf16x8;
typedef __attribute__((ext_vector_type(4))) float f32x4;

__device__ __forceinline__ float bf2f(u16 u) {
    union { unsigned int i; float f; } v;
    v.i = ((unsigned int)u) << 16;
    return v.f;
}
__device__ __forceinline__ u16 f2bf(float f) {
    union { float f; unsigned int i; } v;
    v.f = f;
    unsigned int x = v.i;
    unsigned int r = (x >> 16) & 1u;
    x += 0x7fffu + r;           // round-to-nearest-even
    return (u16)(x >> 16);
}

// ---------------------------------------------------------------------------
// k_prep: blocks 0..4095 geo | 4096..5119 wtrans | 5120..8191 X->bf16 cvt.
// (r16 verbatim)
// ---------------------------------------------------------------------------
__global__ __launch_bounds__(256) void k_prep(const float* __restrict__ box,
                                              const float* __restrict__ Wg,
                                              const float* __restrict__ bg,
                                              u16* __restrict__ Sg,
                                              const float* __restrict__ W0,
                                              const float* __restrict__ W1,
                                              const float* __restrict__ W2,
                                              const float* __restrict__ W3,
                                              u16* __restrict__ Wt,
                                              const float* __restrict__ X0,
                                              const float* __restrict__ X1,
                                              const float* __restrict__ X2,
                                              u16* __restrict__ Xb) {
    const int tid = threadIdx.x;
    const int bid = blockIdx.x;
    if (bid < 4096) {
        __shared__ float sWg[8][64];
        __shared__ float sbg[8];
        if (tid < 8) sbg[tid] = bg[tid];
        { int e = tid; sWg[e >> 6][e & 63] = Wg[e];
          e = tid + 256; sWg[e >> 6][e & 63] = Wg[e]; }
        const int bi = bid, b = bi >> 8;
        float4 bxi = *(const float4*)&box[(size_t)bi * 4];
        float4 bxj = *(const float4*)&box[(size_t)(b * N_ + tid) * 4];
        __syncthreads();
        float cxi = (bxi.x + bxi.z) * 0.5f, cyi = (bxi.y + bxi.w) * 0.5f;
        float wi = bxi.z - bxi.x + 1.0f, hi = bxi.w - bxi.y + 1.0f;
        float cxj = (bxj.x + bxj.z) * 0.5f, cyj = (bxj.y + bxj.w) * 0.5f;
        float wj = bxj.z - bxj.x + 1.0f, hj = bxj.w - bxj.y + 1.0f;
        float pos[4];
        pos[0] = __logf(fmaxf(fabsf((cxi - cxj) / wi), 1e-3f));
        pos[1] = __logf(fmaxf(fabsf((cyi - cyj) / hi), 1e-3f));
        pos[2] = __logf(wi / wj);
        pos[3] = __logf(hi / hj);
        const float dm[8] = {1.0f, 0.42169650342858224f, 0.1778279410038923f,
                             0.07498942093324559f, 0.03162277660168379f,
                             0.013335214321633241f, 0.005623413251903491f,
                             0.0023713737056616554f};
        const float inv2pi = 0.15915494309189535f;
        float acc[8];
#pragma unroll
        for (int h = 0; h < 8; ++h) acc[h] = sbg[h];
#pragma unroll
        for (int t = 0; t < 4; ++t) {
            float base = 100.0f * pos[t];
#pragma unroll
            for (int f = 0; f < 8; ++f) {
                float rev = base * dm[f] * inv2pi;
                rev = rev - floorf(rev);
                float sn = __builtin_amdgcn_sinf(rev);
                float cs = __builtin_amdgcn_cosf(rev);
                int idx = t * 8 + f;
#pragma unroll
                for (int h = 0; h < 8; ++h)
                    acc[h] += sWg[h][idx] * sn + sWg[h][idx + 32] * cs;
            }
        }
        const int i = bi & 255;
#pragma unroll
        for (int h = 0; h < 8; ++h)
            Sg[(((size_t)(b * H_ + h) * N_) + i) * N_ + tid] =
                f2bf(__logf(fmaxf(acc[h], 1e-6f)));
    } else if (bid < 5120) {
        __shared__ float tt[32][33];
        int t = bid - 4096;
        int z = t >> 8, yb = (t >> 4) & 15, xb = t & 15;
        const float* W = (z == 0) ? W0 : (z == 1) ? W1 : (z == 2) ? W2 : W3;
        u16* dst = Wt + (size_t)z * 262144;
        const int kb = yb * 32, nb = xb * 32;
#pragma unroll
        for (int r = 0; r < 4; ++r) {
            int p = r * 256 + tid;
            tt[p >> 5][p & 31] = W[(size_t)(kb + (p >> 5)) * 512 + nb + (p & 31)];
        }
        __syncthreads();
#pragma unroll
        for (int r = 0; r < 4; ++r) {
            int p = r * 256 + tid;
            dst[(size_t)(nb + (p >> 5)) * 512 + kb + (p & 31)] = f2bf(tt[p & 31][p >> 5]);
        }
    } else {
        int t = bid - 5120;
        int z = t >> 10, x = t & 1023;
        const float* X = (z == 0) ? X0 : (z == 1) ? X1 : X2;
        u16* dst = Xb + (size_t)z * 2097152;
        int base = (x * 256 + tid) * 8;
        float4 a = *(const float4*)&X[base];
        float4 b = *(const float4*)&X[base + 4];
        ushort4 oa, ob;
        oa.x = f2bf(a.x); oa.y = f2bf(a.y); oa.z = f2bf(a.z); oa.w = f2bf(a.w);
        ob.x = f2bf(b.x); ob.y = f2bf(b.y); ob.z = f2bf(b.z); ob.w = f2bf(b.w);
        *(ushort4*)&dst[base] = oa;
        *(ushort4*)&dst[base + 4] = ob;
    }
}

// ---------------------------------------------------------------------------
// k_gemm_qkv: r16 verbatim (XCD swizzle: grid (64,8,3), id%8 = m%8).
// ---------------------------------------------------------------------------
__global__ __launch_bounds__(256) void k_gemm_qkv(const u16* __restrict__ Xb,
                                                  const u16* __restrict__ Wtb,
                                                  const float* __restrict__ bq,
                                                  const float* __restrict__ bk,
                                                  const float* __restrict__ bv,
                                                  u16* __restrict__ qkv) {
    const int z = blockIdx.z;
    const u16* Ab = Xb + (size_t)z * 2097152;
    const u16* Wt = Wtb + (size_t)z * 262144;
    const float* bias = (z == 0) ? bq : (z == 1) ? bk : bv;
    u16* dst = qkv + (size_t)z * 2097152;

    __shared__ u16 As[2][64][72];
    __shared__ u16 Bs[2][64][72];
    const int tid = threadIdx.x;
    const int m0 = blockIdx.x * 64, n0 = blockIdx.y * 64;
    const int wid = tid >> 6, lane = tid & 63;
    const int wm = (wid & 1) * 32, wn = (wid >> 1) * 32;
    const int lr = lane & 15, lk8 = (lane >> 4) * 8, quad4 = (lane >> 4) * 4;

    f32x4 acc[2][2];
#pragma unroll
    for (int mi = 0; mi < 2; ++mi)
#pragma unroll
        for (int ni = 0; ni < 2; ++ni) acc[mi][ni] = (f32x4){0.f, 0.f, 0.f, 0.f};

    ushort4 ra[4], rb[4];
#pragma unroll
    for (int r = 0; r < 4; ++r) {
        int p = r * 256 + tid, row = p >> 4, c4 = (p & 15) * 4;
        ra[r] = *(const ushort4*)&Ab[(size_t)(m0 + row) * 512 + c4];
        rb[r] = *(const ushort4*)&Wt[(size_t)(n0 + row) * 512 + c4];
    }
#pragma unroll
    for (int r = 0; r < 4; ++r) {
        int p = r * 256 + tid, row = p >> 4, c4 = (p & 15) * 4;
        *(ushort4*)&As[0][row][c4] = ra[r];
        *(ushort4*)&Bs[0][row][c4] = rb[r];
    }
    __syncthreads();
    for (int it = 0; it < 8; ++it) {
        const int cur = it & 1;
        if (it < 7) {
            int k0n = (it + 1) * 64;
#pragma unroll
            for (int r = 0; r < 4; ++r) {
                int p = r * 256 + tid, row = p >> 4, c4 = (p & 15) * 4;
                ra[r] = *(const ushort4*)&Ab[(size_t)(m0 + row) * 512 + k0n + c4];
                rb[r] = *(const ushort4*)&Wt[(size_t)(n0 + row) * 512 + k0n + c4];
            }
        }
#pragma unroll
        for (int ks = 0; ks < 64; ks += 32) {
            bf16x8 af[2], bfx[2];
#pragma unroll
            for (int mi = 0; mi < 2; ++mi)
                af[mi] = *(const bf16x8*)&As[cur][wm + mi * 16 + lr][ks + lk8];
#pragma unroll
            for (int ni = 0; ni < 2; ++ni)
                bfx[ni] = *(const bf16x8*)&Bs[cur][wn + ni * 16 + lr][ks + lk8];
#pragma unroll
            for (int mi = 0; mi < 2; ++mi)
#pragma unroll
                for (int ni = 0; ni < 2; ++ni)
                    acc[mi][ni] = __builtin_amdgcn_mfma_f32_16x16x32_bf16(
                        af[mi], bfx[ni], acc[mi][ni], 0, 0, 0);
        }
        if (it < 7) {
#pragma unroll
            for (int r = 0; r < 4; ++r) {
                int p = r * 256 + tid, row = p >> 4, c4 = (p & 15) * 4;
                *(ushort4*)&As[1 - cur][row][c4] = ra[r];
                *(ushort4*)&Bs[1 - cur][row][c4] = rb[r];
            }
            __syncthreads();
        }
    }
    u16* bounce = &As[0][0][0];
    const float scale = (z == 0) ? 0.125f : 1.0f;
    const int h = n0 >> 6, b = m0 >> 8, rrb = m0 & 255;
    if (z == 2) {
#pragma unroll
        for (int mi = 0; mi < 2; ++mi)
#pragma unroll
            for (int ni = 0; ni < 2; ++ni) {
                int cn = wn + ni * 16 + lr;
                float bb = bias[n0 + cn];
#pragma unroll
                for (int reg = 0; reg < 4; ++reg) {
                    int rm = wm + mi * 16 + quad4 + reg;
                    bounce[cn * 72 + rm] = f2bf(acc[mi][ni][reg] + bb);
                }
            }
        __syncthreads();
#pragma unroll
        for (int r = 0; r < 4; ++r) {
            int p = r * 256 + tid, dn = p >> 4, c4 = (p & 15) * 4;
            *(ushort4*)&dst[(((size_t)(b * H_ + h) * DK_) + dn) * N_ + rrb + c4] =
                *(const ushort4*)&bounce[dn * 72 + c4];
        }
    } else {
#pragma unroll
        for (int mi = 0; mi < 2; ++mi)
#pragma unroll
            for (int ni = 0; ni < 2; ++ni) {
                int cn = wn + ni * 16 + lr;
                float bb = bias[n0 + cn];
#pragma unroll
                for (int reg = 0; reg < 4; ++reg) {
                    int rm = wm + mi * 16 + quad4 + reg;
                    bounce[rm * 72 + cn] = f2bf((acc[mi][ni][reg] + bb) * scale);
                }
            }
        __syncthreads();
#pragma unroll
        for (int r = 0; r < 4; ++r) {
            int p = r * 256 + tid, rm = p >> 4, c4 = (p & 15) * 4;
            *(ushort4*)&dst[(((size_t)(b * H_ + h) * N_) + rrb + rm) * DK_ + c4] =
                *(const ushort4*)&bounce[rm * 72 + c4];
        }
    }
}

// ---------------------------------------------------------------------------
// k_gemm_out: r16 verbatim (XCD swizzle grid (64,8)).
// ---------------------------------------------------------------------------
__global__ __launch_bounds__(256) void k_gemm_out(const u16* __restrict__ Ab,
                                                  const u16* __restrict__ Wt,
                                                  const float* __restrict__ bias,
                                                  float* __restrict__ outp) {
    __shared__ u16 As[2][64][72];
    __shared__ u16 Bs[2][64][72];
    const int tid = threadIdx.x;
    const int m0 = blockIdx.x * 64, n0 = blockIdx.y * 64;
    const int wid = tid >> 6, lane = tid & 63;
    const int wm = (wid & 1) * 32, wn = (wid >> 1) * 32;
    const int lr = lane & 15, lk8 = (lane >> 4) * 8;
    f32x4 acc[2][2];
#pragma unroll
    for (int mi = 0; mi < 2; ++mi)
#pragma unroll
        for (int ni = 0; ni < 2; ++ni) acc[mi][ni] = (f32x4){0.f, 0.f, 0.f, 0.f};
    ushort4 ra[4], rb[4];
#pragma unroll
    for (int r = 0; r < 4; ++r) {
        int p = r * 256 + tid, row = p >> 4, c4 = (p & 15) * 4;
        ra[r] = *(const ushort4*)&Ab[(size_t)(m0 + row) * 512 + c4];
        rb[r] = *(const ushort4*)&Wt[(size_t)(n0 + row) * 512 + c4];
    }
#pragma unroll
    for (int r = 0; r < 4; ++r) {
        int p = r * 256 + tid, row = p >> 4, c4 = (p & 15) * 4;
        *(ushort4*)&As[0][row][c4] = ra[r];
        *(ushort4*)&Bs[0][row][c4] = rb[r];
    }
    __syncthreads();
    for (int it = 0; it < 8; ++it) {
        const int cur = it & 1;
        if (it < 7) {
            int k0n = (it + 1) * 64;
#pragma unroll
            for (int r = 0; r < 4; ++r) {
                int p = r * 256 + tid, row = p >> 4, c4 = (p & 15) * 4;
                ra[r] = *(const ushort4*)&Ab[(size_t)(m0 + row) * 512 + k0n + c4];
                rb[r] = *(const ushort4*)&Wt[(size_t)(n0 + row) * 512 + k0n + c4];
            }
        }
#pragma unroll
        for (int ks = 0; ks < 64; ks += 32) {
            bf16x8 af[2], bfx[2];
#pragma unroll
            for (int mi = 0; mi < 2; ++mi)
                af[mi] = *(const bf16x8*)&As[cur][wm + mi * 16 + lr][ks + lk8];
#pragma unroll
            for (int ni = 0; ni < 2; ++ni)
                bfx[ni] = *(const bf16x8*)&Bs[cur][wn + ni * 16 + lr][ks + lk8];
#pragma unroll
            for (int mi = 0; mi < 2; ++mi)
#pragma unroll
                for (int ni = 0; ni < 2; ++ni)
                    acc[mi][ni] = __builtin_amdgcn_mfma_f32_16x16x32_bf16(
                        af[mi], bfx[ni], acc[mi][ni], 0, 0, 0);
        }
        if (it < 7) {
#pragma unroll
            for (int r = 0; r < 4; ++r) {
                int p = r * 256 + tid, row = p >> 4, c4 = (p & 15) * 4;
                *(ushort4*)&As[1 - cur][row][c4] = ra[r];
                *(ushort4*)&Bs[1 - cur][row][c4] = rb[r];
            }
            __syncthreads();
        }
    }
#pragma unroll
    for (int mi = 0; mi < 2; ++mi)
#pragma unroll
        for (int ni = 0; ni < 2; ++ni) {
            int col = n0 + wn + ni * 16 + lr;
            float bb = bias[col];
#pragma unroll
            for (int reg = 0; reg < 4; ++reg) {
                int m = m0 + wm + mi * 16 + (lane >> 4) * 4 + reg;
                outp[(size_t)m * 512 + col] = acc[mi][ni][reg] + bb;
            }
        }
}

// ---------------------------------------------------------------------------
// k_attn v4: 64-row i-tile (2x amortization of K/V staging, barriers, softmax
// machinery). LDS 63.5 KB -> 2 blocks/CU; grid (128 bh, 4 i-tiles) = 512
// blocks = exactly 2/CU; id%8 = bh%8 keeps XCD K/V/Sg locality.
// ---------------------------------------------------------------------------
__global__ __launch_bounds__(256) void k_attn(const u16* __restrict__ qh,
                                              const u16* __restrict__ kh,
                                              const u16* __restrict__ vhT,
                                              const u16* __restrict__ Sg,
                                              u16* __restrict__ attnb) {
    __shared__ __align__(16) unsigned char smem[63488];
    u16* sQ = (u16*)smem;                     // [64][72]  (9216 B)
    u16* sP = (u16*)(smem + 9216);            // [64][264] (33792 B): bias -> P
    u16* sK = (u16*)(smem + 43008);           // [128][72] (18432 B), aliased:
    u16* sVt = (u16*)(smem + 43008);          // [64][136] (17408 B)
    float* sRedM = (float*)(smem + 61440);    // [64][4]
    float* sRedS = (float*)(smem + 62464);    // [64][4]

    const int tid = threadIdx.x;
    const int bh = blockIdx.x;                 // XCD swizzle: id%8 = bh%8
    const int i0 = blockIdx.y * 64;
    const int b = bh >> 3, h = bh & 7;
    const int wid = tid >> 6, lane = tid & 63;
    const int lr = lane & 15, lk8 = (lane >> 4) * 8, quad4 = (lane >> 4) * 4;

    // ---- stage Q (64x64), bias (64x256), K chunk 0 (128x64) ----
#pragma unroll
    for (int r = 0; r < 4; ++r) {
        int p = r * 256 + tid, i = p >> 4, d0 = (p & 15) * 4;
        *(ushort4*)&sQ[i * 72 + d0] =
            *(const ushort4*)&qh[((size_t)bh * N_ + i0 + i) * DK_ + d0];
    }
#pragma unroll
    for (int r = 0; r < 16; ++r) {
        int p = r * 256 + tid, row = p >> 6, jc = (p & 63) * 4;
        *(ushort4*)&sP[row * 264 + jc] =
            *(const ushort4*)&Sg[(((size_t)bh * N_) + i0 + row) * N_ + jc];
    }
#pragma unroll
    for (int r = 0; r < 8; ++r) {
        int p = r * 256 + tid, j = p >> 4, d0 = (p & 15) * 4;
        *(ushort4*)&sK[j * 72 + d0] =
            *(const ushort4*)&kh[((size_t)bh * N_ + j) * DK_ + d0];
    }
    __syncthreads();

    // ---- K chunk-1 prefetch into regs; QK^T chunk 0 ----
    ushort4 kpre[8];
#pragma unroll
    for (int r = 0; r < 8; ++r) {
        int p = r * 256 + tid, j = p >> 4, d0 = (p & 15) * 4;
        kpre[r] = *(const ushort4*)&kh[((size_t)bh * N_ + 128 + j) * DK_ + d0];
    }
    f32x4 acc[2][4][2];   // [chunk][mi][ni]
#pragma unroll
    for (int c = 0; c < 2; ++c)
#pragma unroll
        for (int mi = 0; mi < 4; ++mi)
#pragma unroll
            for (int ni = 0; ni < 2; ++ni) acc[c][mi][ni] = (f32x4){0.f, 0.f, 0.f, 0.f};
#pragma unroll
    for (int ks = 0; ks < 64; ks += 32) {
        bf16x8 af[4], bfx[2];
#pragma unroll
        for (int mi = 0; mi < 4; ++mi)
            af[mi] = *(const bf16x8*)&sQ[(mi * 16 + lr) * 72 + ks + lk8];
#pragma unroll
        for (int ni = 0; ni < 2; ++ni)
            bfx[ni] = *(const bf16x8*)&sK[(wid * 32 + ni * 16 + lr) * 72 + ks + lk8];
#pragma unroll
        for (int mi = 0; mi < 4; ++mi)
#pragma unroll
            for (int ni = 0; ni < 2; ++ni)
                acc[0][mi][ni] = __builtin_amdgcn_mfma_f32_16x16x32_bf16(
                    af[mi], bfx[ni], acc[0][mi][ni], 0, 0, 0);
    }
    __syncthreads();
#pragma unroll
    for (int r = 0; r < 8; ++r) {
        int p = r * 256 + tid, j = p >> 4, d0 = (p & 15) * 4;
        *(ushort4*)&sK[j * 72 + d0] = kpre[r];
    }
    __syncthreads();
#pragma unroll
    for (int ks = 0; ks < 64; ks += 32) {
        bf16x8 af[4], bfx[2];
#pragma unroll
        for (int mi = 0; mi < 4; ++mi)
            af[mi] = *(const bf16x8*)&sQ[(mi * 16 + lr) * 72 + ks + lk8];
#pragma unroll
        for (int ni = 0; ni < 2; ++ni)
            bfx[ni] = *(const bf16x8*)&sK[(wid * 32 + ni * 16 + lr) * 72 + ks + lk8];
#pragma unroll
        for (int mi = 0; mi < 4; ++mi)
#pragma unroll
            for (int ni = 0; ni < 2; ++ni)
                acc[1][mi][ni] = __builtin_amdgcn_mfma_f32_16x16x32_bf16(
                    af[mi], bfx[ni], acc[1][mi][ni], 0, 0, 0);
    }
    __syncthreads();   // sK dead

    // ---- stage V chunk 0 (overlaps softmax A) ----
#pragma unroll
    for (int r = 0; r < 8; ++r) {
        int p = r * 256 + tid, d = p >> 5, jc = (p & 31) * 4;
        *(ushort4*)&sVt[d * 136 + jc] =
            *(const ushort4*)&vhT[(((size_t)bh * DK_) + d) * N_ + jc];
    }
    // ---- softmax A: add bias, per-row max ----
#pragma unroll
    for (int c = 0; c < 2; ++c)
#pragma unroll
        for (int mi = 0; mi < 4; ++mi)
#pragma unroll
            for (int ni = 0; ni < 2; ++ni) {
                int col = c * 128 + wid * 32 + ni * 16 + lr;
#pragma unroll
                for (int reg = 0; reg < 4; ++reg) {
                    int row = mi * 16 + quad4 + reg;
                    acc[c][mi][ni][reg] += bf2f(sP[row * 264 + col]);
                }
            }
    float mrow[4][4];
#pragma unroll
    for (int mi = 0; mi < 4; ++mi)
#pragma unroll
        for (int reg = 0; reg < 4; ++reg) {
            float m = acc[0][mi][0][reg];
            m = fmaxf(m, acc[0][mi][1][reg]);
            m = fmaxf(m, acc[1][mi][0][reg]);
            m = fmaxf(m, acc[1][mi][1][reg]);
#pragma unroll
            for (int off = 1; off <= 8; off <<= 1) m = fmaxf(m, __shfl_xor(m, off, 64));
            mrow[mi][reg] = m;
        }
    if (lr == 0) {
#pragma unroll
        for (int mi = 0; mi < 4; ++mi)
#pragma unroll
            for (int reg = 0; reg < 4; ++reg)
                sRedM[(mi * 16 + quad4 + reg) * 4 + wid] = mrow[mi][reg];
    }
    __syncthreads();
    // ---- softmax B: global max, exp, per-row sum ----
    float gm[4][4], sl[4][4];
#pragma unroll
    for (int mi = 0; mi < 4; ++mi)
#pragma unroll
        for (int reg = 0; reg < 4; ++reg) {
            float4 mm = *(const float4*)&sRedM[(mi * 16 + quad4 + reg) * 4];
            gm[mi][reg] = fmaxf(fmaxf(mm.x, mm.y), fmaxf(mm.z, mm.w));
            sl[mi][reg] = 0.f;
        }
#pragma unroll
    for (int c = 0; c < 2; ++c)
#pragma unroll
        for (int mi = 0; mi < 4; ++mi)
#pragma unroll
            for (int ni = 0; ni < 2; ++ni)
#pragma unroll
                for (int reg = 0; reg < 4; ++reg) {
                    float e = __expf(acc[c][mi][ni][reg] - gm[mi][reg]);
                    acc[c][mi][ni][reg] = e;
                    sl[mi][reg] += e;
                }
#pragma unroll
    for (int mi = 0; mi < 4; ++mi)
#pragma unroll
        for (int reg = 0; reg < 4; ++reg) {
            float s = sl[mi][reg];
#pragma unroll
            for (int off = 1; off <= 8; off <<= 1) s += __shfl_xor(s, off, 64);
            sl[mi][reg] = s;
        }
    if (lr == 0) {
#pragma unroll
        for (int mi = 0; mi < 4; ++mi)
#pragma unroll
            for (int reg = 0; reg < 4; ++reg)
                sRedS[(mi * 16 + quad4 + reg) * 4 + wid] = sl[mi][reg];
    }
    __syncthreads();
    // ---- softmax C: normalize, write P bf16 ----
#pragma unroll
    for (int mi = 0; mi < 4; ++mi)
#pragma unroll
        for (int reg = 0; reg < 4; ++reg) {
            float4 ss = *(const float4*)&sRedS[(mi * 16 + quad4 + reg) * 4];
            gm[mi][reg] = 1.0f / (ss.x + ss.y + ss.z + ss.w);   // reuse gm = inv
        }
#pragma unroll
    for (int c = 0; c < 2; ++c)
#pragma unroll
        for (int mi = 0; mi < 4; ++mi)
#pragma unroll
            for (int ni = 0; ni < 2; ++ni) {
                int col = c * 128 + wid * 32 + ni * 16 + lr;
#pragma unroll
                for (int reg = 0; reg < 4; ++reg) {
                    int row = mi * 16 + quad4 + reg;
                    sP[row * 264 + col] = f2bf(acc[c][mi][ni][reg] * gm[mi][reg]);
                }
            }
    __syncthreads();   // P + V0 committed

    // ---- PV chunk 0 ----
    f32x4 o[4];
#pragma unroll
    for (int mi = 0; mi < 4; ++mi) o[mi] = (f32x4){0.f, 0.f, 0.f, 0.f};
#pragma unroll
    for (int k0 = 0; k0 < 128; k0 += 32) {
        bf16x8 bfx = *(const bf16x8*)&sVt[(wid * 16 + lr) * 136 + k0 + lk8];
#pragma unroll
        for (int mi = 0; mi < 4; ++mi) {
            bf16x8 af = *(const bf16x8*)&sP[(mi * 16 + lr) * 264 + k0 + lk8];
            o[mi] = __builtin_amdgcn_mfma_f32_16x16x32_bf16(af, bfx, o[mi], 0, 0, 0);
        }
    }
    __syncthreads();
    // ---- stage V chunk 1; PV chunk 1 ----
#pragma unroll
    for (int r = 0; r < 8; ++r) {
        int p = r * 256 + tid, d = p >> 5, jc = (p & 31) * 4;
        *(ushort4*)&sVt[d * 136 + jc] =
            *(const ushort4*)&vhT[(((size_t)bh * DK_) + d) * N_ + 128 + jc];
    }
    __syncthreads();
#pragma unroll
    for (int k0 = 0; k0 < 128; k0 += 32) {
        bf16x8 bfx = *(const bf16x8*)&sVt[(wid * 16 + lr) * 136 + k0 + lk8];
#pragma unroll
        for (int mi = 0; mi < 4; ++mi) {
            bf16x8 af = *(const bf16x8*)&sP[(mi * 16 + lr) * 264 + 128 + k0 + lk8];
            o[mi] = __builtin_amdgcn_mfma_f32_16x16x32_bf16(af, bfx, o[mi], 0, 0, 0);
        }
    }
#pragma unroll
    for (int mi = 0; mi < 4; ++mi)
#pragma unroll
        for (int reg = 0; reg < 4; ++reg) {
            int row = mi * 16 + quad4 + reg;
            attnb[((size_t)(b * N_ + i0 + row)) * D_ + h * 64 + wid * 16 + lr] =
                f2bf(o[mi][reg]);
        }
}

extern "C" void kernel_launch(void* const* d_in, const int* in_sizes, int n_in,
                              void* d_out, int out_size, void* d_ws, size_t ws_size,
                              hipStream_t stream) {
    const float* Xq = (const float*)d_in[0];
    const float* Xk = (const float*)d_in[1];
    const float* Xv = (const float*)d_in[2];
    const float* box = (const float*)d_in[3];
    const float* Wq = (const float*)d_in[4];
    const float* bq = (const float*)d_in[5];
    const float* Wk = (const float*)d_in[6];
    const float* bk = (const float*)d_in[7];
    const float* Wv = (const float*)d_in[8];
    const float* bv = (const float*)d_in[9];
    const float* Wo = (const float*)d_in[10];
    const float* bo = (const float*)d_in[11];
    const float* Wg = (const float*)d_in[12];
    const float* bg = (const float*)d_in[13];
    float* out = (float*)d_out;

    // ws (u16 units): [0,6M) qkv | [6M,14.39M) Sg | [14M,16M) attnb |
    // [16M,17.05M) Wt | [18M,24.3M) Xb.
    u16* ws16 = (u16*)d_ws;
    u16* qkv = ws16;
    u16* qh = qkv;
    u16* kh = qkv + 2097152;
    u16* vhT = qkv + 4194304;
    u16* Sg = ws16 + 6291456;
    u16* attnb = ws16 + 14680064;
    u16* Wt = ws16 + 16777216;
    u16* Xb = ws16 + 18874368;

    dim3 blk(256);
    k_prep<<<dim3(8192), blk, 0, stream>>>(box, Wg, bg, Sg, Wq, Wk, Wv, Wo, Wt,
                                           Xq, Xk, Xv, Xb);
    k_gemm_qkv<<<dim3(64, 8, 3), blk, 0, stream>>>(Xb, Wt, bq, bk, bv, qkv);
    k_attn<<<dim3(128, 4), blk, 0, stream>>>(qh, kh, vhT, Sg, attnb);
    k_gemm_out<<<dim3(64, 8), blk, 0, stream>>>(attnb, Wt + 3 * 262144, bo, out);
}